// Round 4
// baseline (305.034 us; speedup 1.0000x reference)
//
#include <hip/hip_runtime.h>

namespace {
constexpr int kBB = 64, kH = 64, kW = 64, kC = 128, kP = 64;
constexpr int kHW = kH * kW;                 // 4096
constexpr long kRows = (long)kBB * kHW;      // 262144
constexpr long kOutElems = kRows * kC;       // 33554432

typedef float f32x4 __attribute__((ext_vector_type(4)));  // nontemporal-compatible

// Fused per 64-row block:
//   (a) out[row][c] = sum_p s[row][p] * k[p][c]   (s via LDS broadcast, k via L1/L2)
//   (b) zsum[b][c] += sum_rows z[row][c], z2[b] += sum z^2  (atomics, 33/block)
// LDS = s 16KB + red 2KB + qred -> ~18.5KB -> 4 blocks/CU with launch_bounds(256,4).
__global__ __launch_bounds__(256, 4) void fused_kernel(const float* __restrict__ z,
                                                       const float* __restrict__ s,
                                                       const float* __restrict__ kmat,
                                                       float* __restrict__ out,
                                                       float* __restrict__ zsum,
                                                       float* __restrict__ z2) {
  __shared__ f32x4 s_lds[64][kP / 4];   // 16 KB
  __shared__ f32x4 red[4][32];          // 2 KB (per-wave z column partials)
  __shared__ float qred[4];

  const int t = threadIdx.x;
  const int cq = t & 31;   // float4-column 0..31
  const int tg = t >> 5;   // row-group 0..7
  const int w = t >> 6;    // wave 0..3
  const long rowbase = (long)blockIdx.x * 64;
  const int b = (int)(rowbase >> 12);    // 4096 rows per batch image

  // ---- stage s tile (contiguous 16 KB), nontemporal (streamed once) ----
  const f32x4* s4 = reinterpret_cast<const f32x4*>(s + rowbase * kP);
  f32x4* s_flat = &s_lds[0][0];
#pragma unroll
  for (int i = 0; i < 4; ++i) s_flat[t + 256 * i] = __builtin_nontemporal_load(&s4[t + 256 * i]);

  // ---- stream this block's 64 z rows; per-thread partial over its 8 rows ----
  const f32x4* z4 = reinterpret_cast<const f32x4*>(z + rowbase * kC);
  float sx = 0.f, sy = 0.f, sz = 0.f, sw = 0.f, q = 0.f;
#pragma unroll
  for (int j = 0; j < 8; ++j) {
    const f32x4 v = __builtin_nontemporal_load(&z4[(tg + 8 * j) * 32 + cq]);
    sx += v.x; sy += v.y; sz += v.z; sw += v.w;
    q += v.x * v.x + v.y * v.y + v.z * v.z + v.w * v.w;
  }
  // fold lane <-> lane+32 (the two tg groups of this wave share cq)
  sx += __shfl_xor(sx, 32, 64);
  sy += __shfl_xor(sy, 32, 64);
  sz += __shfl_xor(sz, 32, 64);
  sw += __shfl_xor(sw, 32, 64);
  for (int off = 32; off > 0; off >>= 1) q += __shfl_down(q, off, 64);
  if ((t & 63) == 0) qred[w] = q;
  if ((t & 63) < 32) { f32x4 r = {sx, sy, sz, sw}; red[w][cq] = r; }

  __syncthreads();  // covers s staging + red/qred

  // ---- finish z reduction: one wave folds 4 per-wave partials, atomics into ws ----
  if (t < 32) {
    const f32x4 a0 = red[0][t], a1 = red[1][t], a2 = red[2][t], a3 = red[3][t];
    const float tx = a0.x + a1.x + a2.x + a3.x;
    const float ty = a0.y + a1.y + a2.y + a3.y;
    const float tz = a0.z + a1.z + a2.z + a3.z;
    const float tw = a0.w + a1.w + a2.w + a3.w;
    atomicAdd(&zsum[b * kC + t * 4 + 0], tx);
    atomicAdd(&zsum[b * kC + t * 4 + 1], ty);
    atomicAdd(&zsum[b * kC + t * 4 + 2], tz);
    atomicAdd(&zsum[b * kC + t * 4 + 3], tw);
    if (t == 0) atomicAdd(&z2[b], qred[0] + qred[1] + qred[2] + qred[3]);
  }

  // ---- GEMM: each thread 8 rows x 1 float4 of c; k straight from L1/L2 ----
  const f32x4* k4 = reinterpret_cast<const f32x4*>(kmat);
  f32x4 acc[8];
#pragma unroll
  for (int j = 0; j < 8; ++j) acc[j] = (f32x4){0.f, 0.f, 0.f, 0.f};

#pragma unroll 4
  for (int pc = 0; pc < 16; ++pc) {  // p in chunks of 4
    const f32x4 k0 = k4[(4 * pc + 0) * 32 + cq];   // 512B/wave, L1-hot
    const f32x4 k1 = k4[(4 * pc + 1) * 32 + cq];
    const f32x4 k2 = k4[(4 * pc + 2) * 32 + cq];
    const f32x4 k3 = k4[(4 * pc + 3) * 32 + cq];
#pragma unroll
    for (int j = 0; j < 8; ++j) {
      const f32x4 sv = s_lds[tg + 8 * j][pc];  // LDS broadcast
      acc[j].x += sv.x * k0.x + sv.y * k1.x + sv.z * k2.x + sv.w * k3.x;
      acc[j].y += sv.x * k0.y + sv.y * k1.y + sv.z * k2.y + sv.w * k3.y;
      acc[j].z += sv.x * k0.z + sv.y * k1.z + sv.z * k2.z + sv.w * k3.z;
      acc[j].w += sv.x * k0.w + sv.y * k1.w + sv.z * k2.w + sv.w * k3.w;
    }
  }

  f32x4* out4 = reinterpret_cast<f32x4*>(out + rowbase * kC);
#pragma unroll
  for (int j = 0; j < 8; ++j)
    __builtin_nontemporal_store(acc[j], &out4[(tg + 8 * j) * 32 + cq]);
}

// distance[b][p] = z2[b] - 2*dot(zsum[b],k[p]) + 4096*||k[p]||^2
__global__ __launch_bounds__(256) void dist_kernel(const float* __restrict__ zsum,
                                                   const float* __restrict__ z2,
                                                   const float* __restrict__ kmat,
                                                   float* __restrict__ dist) {
  const int g = blockIdx.x * 256 + threadIdx.x;  // 0..4095
  const int b = g >> 6;
  const int p = g & 63;
  float dot = 0.f, k2 = 0.f;
  for (int c = 0; c < kC; ++c) {
    const float kv = kmat[p * kC + c];
    dot += zsum[b * kC + c] * kv;
    k2 += kv * kv;
  }
  dist[g] = z2[b] - 2.f * dot + (float)kHW * k2;
}

}  // namespace

extern "C" void kernel_launch(void* const* d_in, const int* in_sizes, int n_in,
                              void* d_out, int out_size, void* d_ws, size_t ws_size,
                              hipStream_t stream) {
  const float* z = (const float*)d_in[0];      // (64,64,64,128)
  const float* s = (const float*)d_in[1];      // (64,64,64,64)
  const float* kmat = (const float*)d_in[2];   // (64,1,1,128)

  float* out = (float*)d_out;                  // 33554432 floats
  float* dist = out + kOutElems;               // 4096 floats

  float* zsum = (float*)d_ws;                  // 64*128 floats
  float* z2 = zsum + kBB * kC;                 // 64 floats

  // zero the atomic accumulators (ws is poisoned 0xAA each call)
  (void)hipMemsetAsync(d_ws, 0, (size_t)(kBB * kC + kBB) * sizeof(float), stream);

  fused_kernel<<<(int)(kRows / 64), 256, 0, stream>>>(z, s, kmat, out, zsum, z2);
  dist_kernel<<<16, 256, 0, stream>>>(zsum, z2, kmat, dist);
}